// Round 7
// baseline (1580.893 us; speedup 1.0000x reference)
//
#include <hip/hip_runtime.h>
#include <stdint.h>

// ---------------------------------------------------------------------------
// FixedPointLSTM (B=64, T=256, I=512, H=1024), fixed-point Q8.8 with hard
// activations. All fxp grid values are exactly representable in fp16; fp16
// MFMA with fp32 accumulate matches the numpy reference to ~1 grid step.
//
// R17: FLAGLESS self-validating h publication (structural, on the R13 base).
// Ledger: R11 FAIL, R12 -30us, R13 +7us (kept), R14 -315us, R15 0, R16
// -174us. All kept the flag indirection: drain -> flag -> poll -> load =
// ~4 serial L3/cross-XCD legs per step = the 65% stall.
// R17: h in [-1,1] on the 1/256 grid needs 10 bits. Publish m = h*256+256
// with an epoch-parity tag in bit15 of EVERY fp16 slot. Producer 8B stores
// are single-copy atomic -> every staged u64 self-validates (4 tagged
// halves). The consumer's stage load IS the poll: no flags, no w0 poll, no
// drain barrier, no barrier B. Epochs: slot t&1; expected tag (t>>1)&1;
// published tag ((t+1)>>1)&1. 2-slot overrun impossible: producer's step
// t+1 stage transitively requires every consumer's step-t stage.
// Decode is BIT-EXACT: f16bits = 0x3C00 + (m<<1) == 1.5 + h/2 exactly
// (ADD handles the m=512 carry -> 2.0); h = 2f-3 exact (Sterbenz). MFMA
// inputs bitwise identical to R13. hs double-buffered -> ONE barrier/step.
// Slot 1 poisoned 0x80 (tag=1) so t=1 cannot validate stale memory; qh0
// writes encoded tag-0 data.
// ---------------------------------------------------------------------------

typedef _Float16 h8 __attribute__((ext_vector_type(8)));
typedef _Float16 h4 __attribute__((ext_vector_type(4)));
typedef _Float16 h2 __attribute__((ext_vector_type(2)));
typedef float f4 __attribute__((ext_vector_type(4)));
typedef unsigned long long u64;

#define MFMA16(a, b, c) __builtin_amdgcn_mfma_f32_16x16x32_f16(a, b, c, 0, 0, 0)
#define AL(p) __hip_atomic_load((p), __ATOMIC_RELAXED, __HIP_MEMORY_SCOPE_AGENT)

__device__ __forceinline__ float fxp(float x) {
  float q = rintf(x * 256.0f) * 0.00390625f;
  return fminf(fmaxf(q, -128.0f), 127.99609375f);
}

// round-only: for values provably in [-128, 127.996] the clamp is a no-op.
__device__ __forceinline__ float fxp_rnd(float x) {
  return rintf(x * 256.0f) * 0.00390625f;
}

__device__ __forceinline__ float hsig(float x) {
  return fminf(fmaxf(x / 6.0f + 0.5f, 0.0f), 1.0f);  // IEEE div to match np
}

// decode one u64 = 4 tagged halves -> 4 exact fp16 h values.
// bits: m = half & 0x7FFF in [0,512]; f = 0x3C00 + (m<<1) == 1.5 + h/2
// exactly (m=512 carries to 0x4000 = 2.0). h = 2f - 3, exact by Sterbenz.
__device__ __forceinline__ u64 dec2(u64 x) {
  unsigned lo = (unsigned)x, hi = (unsigned)(x >> 32);
  lo = ((lo & 0x7FFF7FFFu) << 1) + 0x3C003C00u;
  hi = ((hi & 0x7FFF7FFFu) << 1) + 0x3C003C00u;
  h2 a = __builtin_bit_cast(h2, lo);
  h2 b = __builtin_bit_cast(h2, hi);
  const h2 two = {(_Float16)2.0f, (_Float16)2.0f};
  const h2 m3 = {(_Float16)-3.0f, (_Float16)-3.0f};
  a = a * two + m3;
  b = b * two + m3;
  return ((u64)__builtin_bit_cast(unsigned, b) << 32) |
         (u64)__builtin_bit_cast(unsigned, a);
}

// ---- quantize fp32 -> fxp grid, store fp16 ---------------------------------
__global__ void qf16_kernel(const float* __restrict__ in,
                            _Float16* __restrict__ out, int n4) {
  int i = blockIdx.x * 256 + threadIdx.x;
  if (i < n4) {
    float4 v = ((const float4*)in)[i];
    h4 o;
    o[0] = (_Float16)fxp(v.x); o[1] = (_Float16)fxp(v.y);
    o[2] = (_Float16)fxp(v.z); o[3] = (_Float16)fxp(v.w);
    ((h4*)out)[i] = o;
  }
}

// quantize + transpose x: in [64][256][512] -> rows m = t*64+b, [16384][512]
__global__ void qx_kernel(const float* __restrict__ in,
                          _Float16* __restrict__ out) {
  int i4 = blockIdx.x * 256 + threadIdx.x;  // over 16384*128 float4s
  int col4 = i4 & 127;
  int row = i4 >> 7;  // b*256 + t
  int b = row >> 8, tt = row & 255;
  float4 v = ((const float4*)in)[i4];
  h4 o;
  o[0] = (_Float16)fxp(v.x); o[1] = (_Float16)fxp(v.y);
  o[2] = (_Float16)fxp(v.z); o[3] = (_Float16)fxp(v.w);
  ((h4*)out)[(size_t)((tt << 6) + b) * 128 + col4] = o;
}

__global__ void qf32_kernel(const float* __restrict__ in,
                            float* __restrict__ out, int n4) {
  int i = blockIdx.x * 256 + threadIdx.x;
  if (i < n4) {
    float4 v = ((const float4*)in)[i];
    float4 o;
    o.x = fxp(v.x); o.y = fxp(v.y); o.z = fxp(v.z); o.w = fxp(v.w);
    ((float4*)out)[i] = o;
  }
}

// h0 -> hbuf slot 0, ENCODED (m = h*256+256, tag bit15 = 0).
// layout [grp=8][buf=2][row=8][1024] fp16-slots
__global__ void qh0_kernel(const float* __restrict__ in,
                           _Float16* __restrict__ hbuf) {
  int i = blockIdx.x * 256 + threadIdx.x;  // over 64*1024/4
  int col4 = i & 255, b = i >> 8;
  float4 v = ((const float4*)in)[i];
  float x0 = fminf(fmaxf(fxp(v.x), -1.0f), 1.0f);
  float x1 = fminf(fmaxf(fxp(v.y), -1.0f), 1.0f);
  float x2 = fminf(fmaxf(fxp(v.z), -1.0f), 1.0f);
  float x3 = fminf(fmaxf(fxp(v.w), -1.0f), 1.0f);
  h4 o;
  o[0] = __builtin_bit_cast(_Float16, (unsigned short)((int)(x0 * 256.f) + 256));
  o[1] = __builtin_bit_cast(_Float16, (unsigned short)((int)(x1 * 256.f) + 256));
  o[2] = __builtin_bit_cast(_Float16, (unsigned short)((int)(x2 * 256.f) + 256));
  o[3] = __builtin_bit_cast(_Float16, (unsigned short)((int)(x3 * 256.f) + 256));
  *(h4*)(hbuf + (size_t)(b >> 3) * 16384 + (b & 7) * 1024 + col4 * 4) = o;
}

// ---- async global->LDS helper (width 16B; LDS dest = wave-uniform base) ----
__device__ __forceinline__ void gload_lds16(const _Float16* g, _Float16* l) {
  __builtin_amdgcn_global_load_lds(
      (const __attribute__((address_space(1))) uint32_t*)g,
      (__attribute__((address_space(3))) uint32_t*)l, 16, 0, 0);
}

// ---------------------------------------------------------------------------
// gx = fxp(x_q @ w_ih_q^T + b_ih_q), packed [T=256][oct=8][rank=32][slot=128][8]
// fp16 (128 MB). slot = (w<<5)|(qh<<4)|(gate&1)<<3|(j&7); per-entry 8 fp16 =
// [tile0 r=0..3 | tile1 r=0..3], tile = gate>>1, r = b&3, qh = (b>>2)&1.
// (R13 layout, verbatim.)
// ---------------------------------------------------------------------------
__global__ __launch_bounds__(256) void gemm_gx_kernel(
    const _Float16* __restrict__ Xq,   // [16384][512], m = t*64+b
    const _Float16* __restrict__ Wih,  // [4096][512]
    const float* __restrict__ bih,     // [4096]
    _Float16* __restrict__ gx)         // packed, see above
{
  __shared__ _Float16 As[128 * 32];
  __shared__ _Float16 Bs[128 * 32];
  const int tid = threadIdx.x;
  const int lane = tid & 63;
  const int w = tid >> 6;
  const int wm = (w >> 1) * 64;
  const int wn = (w & 1) * 64;
  const int m0 = blockIdx.x * 128;
  const int n0 = blockIdx.y * 128;
  const int cl = lane & 15, q = lane >> 4;

  f4 acc[4][4] = {};

  for (int k0 = 0; k0 < 512; k0 += 32) {
#pragma unroll
    for (int i = 0; i < 2; i++) {
      int idx = i * 256 + tid;
      int row = idx >> 2;
      int kc = (idx & 3) << 3;
      int wbase = (i * 256 + (tid & 192)) << 3;  // wave-uniform LDS base
      gload_lds16(Xq + (size_t)(m0 + row) * 512 + k0 + kc, As + wbase);
      gload_lds16(Wih + (size_t)(n0 + row) * 512 + k0 + kc, Bs + wbase);
    }
    __syncthreads();
    h8 af[4], bf[4];
#pragma unroll
    for (int mt = 0; mt < 4; mt++)
      af[mt] = *(const h8*)(As + (wm + mt * 16 + cl) * 32 + q * 8);
#pragma unroll
    for (int nt = 0; nt < 4; nt++)
      bf[nt] = *(const h8*)(Bs + (wn + nt * 16 + cl) * 32 + q * 8);
#pragma unroll
    for (int mt = 0; mt < 4; mt++)
#pragma unroll
      for (int nt = 0; nt < 4; nt++)
        acc[mt][nt] = MFMA16(af[mt], bf[nt], acc[mt][nt]);
    __syncthreads();
  }

  const int g = n0 >> 10;  // whole n-block lies in one gate
  const int tile = g >> 1, g1 = g & 1;
#pragma unroll
  for (int nt = 0; nt < 4; nt++) {
    const int n = n0 + wn + nt * 16 + cl;
    const float bv = bih[n];
    const int j = n & 1023;
    const int rank = j >> 5, wq = (j >> 3) & 3, c7 = j & 7;
#pragma unroll
    for (int mt = 0; mt < 4; mt++) {
      const int m = m0 + wm + mt * 16 + q * 4;  // 4-aligned
      const int b = m & 63, tt = m >> 6;
      const int oct = b >> 3, qh = (b >> 2) & 1;
      const int slot = (wq << 5) | (qh << 4) | (g1 << 3) | c7;
      h4 pk;
#pragma unroll
      for (int r = 0; r < 4; r++) pk[r] = (_Float16)fxp(acc[mt][nt][r] + bv);
      *(h4*)(gx + ((((size_t)tt * 8 + oct) * 32 + rank) * 128 + slot) * 8 +
             tile * 4) = pk;
    }
  }
}

// ---------------------------------------------------------------------------
// Persistent recurrence. 256 blocks x 256 threads, a255 pin -> 1 block/CU ->
// all blocks co-resident. Block = (grp = blockIdx&7, rank = blockIdx>>3);
// group owns batch rows 8g..8g+7; rank owns h-cols rank*32..+31 x 4 gates
// (128 W_hh rows in regs). Per step (R17 flagless):
//   gx prefetch -> stage-poll: 8x8B agent loads of tagged h, per-u64 parity
//   validate + retry -> decode (bit-exact) -> ds_write_b64 to hs[t&1] ->
//   ONE barrier -> MFMA (reads hs[t&1]) -> gates -> writers deposit ENCODED
//   h to per-wave LDS tile -> lgkm -> lanes 0-15 u64-read + 16x8B agent
//   stores (tag = ((t+1)>>1)&1) -> out stores (plain cached, off path).
// hs double-buffered: stage(t+1) writes hs[(t+1)&1] while nothing reads it;
// safety: any wave reaching stage(t+2) passed barrier(t+1), which requires
// all waves past MFMA(t).
// ---------------------------------------------------------------------------
__global__ __launch_bounds__(256, 1) void lstm_kernel(
    const _Float16* __restrict__ Whh,  // [4096][1024] quantized
    const float* __restrict__ bhh,     // [4096] quantized
    const _Float16* __restrict__ gx,   // packed [256][8][32][128][8]
    const float* __restrict__ c0,      // [64][1024]
    _Float16* __restrict__ hbuf,       // [8][2][8][1024] fp16-slots (encoded)
    float* __restrict__ out,           // [64][256][1024] ++ h_n ++ c_n
    unsigned* __restrict__ flags)      // unused (R17 is flagless)
{
  (void)flags;
  // Residency pin: force total regs/wave > 256 -> 1 wave/SIMD -> 1 block/CU.
  asm volatile("v_accvgpr_write_b32 a255, 0" ::: "a255");

  const int tid = threadIdx.x;
  const int lane = tid & 63;
  const int w = tid >> 6;
  const int cl = lane & 15, q = lane >> 4;
  const int g01 = (lane >> 3) & 1;
  const int c7 = lane & 7;

  const int grp = blockIdx.x & 7;    // batch octet
  const int rank = blockIdx.x >> 3;  // 32-column slice owner

  const int jbase = (rank << 5) + (w << 3);         // block/wave col base
  const int row0 = (g01 << 10) + jbase + c7;        // gates i/f
  const int row1 = ((g01 + 2) << 10) + jbase + c7;  // gates g/o

  // persistent B fragments: 2 tiles x 32 k-steps x 4 regs = 256 regs
  h8 B0[32], B1[32];
#pragma unroll
  for (int kt = 0; kt < 32; kt++) {
    B0[kt] = *(const h8*)(Whh + (size_t)row0 * 1024 + (kt << 5) + (q << 3));
    B1[kt] = *(const h8*)(Whh + (size_t)row1 * 1024 + (kt << 5) + (q << 3));
  }
  const float bh0 = bhh[row0], bh1 = bhh[row1];
  const int jc = jbase + c7;        // h column 0..1023
  const int lrow = ((q & 1) << 2);  // local batch row base (valid q<2)
  const bool writer = ((lane & 8) == 0) && (q < 2);

  float c_st[4], h_last[4];
#pragma unroll
  for (int r = 0; r < 4; r++) {
    c_st[r] = c0[((grp << 3) + lrow + r) * 1024 + jc];
    h_last[r] = 0.0f;
  }

  // LDS: hs double-buffered [2][8][1032] (pad +8: fragment reads arow*1032
  // conflict-free, verified R6) + per-wave 64-half publication tile.
  __shared__ alignas(16) _Float16 hs[2 * 8 * 1032 + 4 * 64];
  const int arow = cl & 7;
  const u64* hb64 = (const u64*)hbuf;  // [grp: 4096][buf: 2048] u64s
  const size_t lsrc = (size_t)grp * 4096 + (size_t)((tid >> 5) << 8) + (tid & 31);
  const int soff = (tid >> 5) * 1032 + ((tid & 31) << 2);
  _Float16* ts = hs + 2 * 8 * 1032 + w * 64;  // per-wave [8 rows][8 cols]

  const u64 TM = 0x8000800080008000ULL;

  for (int t = 0; t < 256; t++) {
    // prefetch gx_t: one coalesced 16B load per lane (overlaps the poll)
    const h8 gv8 = *(const h8*)(
        gx +
        ((((size_t)t * 8 + grp) * 32 + rank) * 128 + ((w << 5) | (lane & 31))) *
            8);

    _Float16* hsb = hs + (t & 1) * 8256;

    // ---- stage-poll: 8x8B tagged loads, per-u64 validate, decode, write --
    {
      const u64* src = hb64 + lsrc + (size_t)(t & 1) * 2048;
      u64 v0 = AL(src + 0 * 32);
      u64 v1 = AL(src + 1 * 32);
      u64 v2 = AL(src + 2 * 32);
      u64 v3 = AL(src + 3 * 32);
      u64 v4 = AL(src + 4 * 32);
      u64 v5 = AL(src + 5 * 32);
      u64 v6 = AL(src + 6 * 32);
      u64 v7 = AL(src + 7 * 32);
      const u64 ET = ((t >> 1) & 1) ? TM : 0ULL;
      int it = 0;
      for (;;) {
        unsigned bad = 0;
        if ((v0 ^ ET) & TM) bad |= 1u;
        if ((v1 ^ ET) & TM) bad |= 2u;
        if ((v2 ^ ET) & TM) bad |= 4u;
        if ((v3 ^ ET) & TM) bad |= 8u;
        if ((v4 ^ ET) & TM) bad |= 16u;
        if ((v5 ^ ET) & TM) bad |= 32u;
        if ((v6 ^ ET) & TM) bad |= 64u;
        if ((v7 ^ ET) & TM) bad |= 128u;
        if (__ballot(bad != 0) == 0) break;
        if (++it > (1 << 14)) break;  // hang insurance (loudly wrong)
        __builtin_amdgcn_s_sleep(2);
        if (bad & 1u) v0 = AL(src + 0 * 32);
        if (bad & 2u) v1 = AL(src + 1 * 32);
        if (bad & 4u) v2 = AL(src + 2 * 32);
        if (bad & 8u) v3 = AL(src + 3 * 32);
        if (bad & 16u) v4 = AL(src + 4 * 32);
        if (bad & 32u) v5 = AL(src + 5 * 32);
        if (bad & 64u) v6 = AL(src + 6 * 32);
        if (bad & 128u) v7 = AL(src + 7 * 32);
      }
      _Float16* ldst = hsb + soff;
      *(u64*)(ldst + 0 * 128) = dec2(v0);
      *(u64*)(ldst + 1 * 128) = dec2(v1);
      *(u64*)(ldst + 2 * 128) = dec2(v2);
      *(u64*)(ldst + 3 * 128) = dec2(v3);
      *(u64*)(ldst + 4 * 128) = dec2(v4);
      *(u64*)(ldst + 5 * 128) = dec2(v5);
      *(u64*)(ldst + 6 * 128) = dec2(v6);
      *(u64*)(ldst + 7 * 128) = dec2(v7);
    }
    __syncthreads();  // the ONLY barrier per step

    f4 a0 = {}, a1 = {}, a2 = {}, a3 = {};
#pragma unroll
    for (int kt = 0; kt < 32; kt++) {
      h8 av = *(const h8*)(hsb + arow * 1032 + (kt << 5) + (q << 3));
      if (kt & 1) { a1 = MFMA16(av, B0[kt], a1); a3 = MFMA16(av, B1[kt], a3); }
      else        { a0 = MFMA16(av, B0[kt], a0); a2 = MFMA16(av, B1[kt], a2); }
    }
    f4 g0 = a0 + a1;
    f4 g1 = a2 + a3;

    const unsigned epub = ((unsigned)(((t + 1) >> 1) & 1)) << 15;
    _Float16* hbw = hbuf + (size_t)grp * 16384 + ((t + 1) & 1) * 8192;
#pragma unroll
    for (int r = 0; r < 4; r++) {
      float gv0 = fxp((float)gv8[r] + fxp(g0[r] + bh0));      // i or f
      float gv1 = fxp((float)gv8[4 + r] + fxp(g1[r] + bh1));  // g or o
      float s0 = fxp_rnd(hsig(gv0));                        // in [0,1]
      float s1t = fxp_rnd(fminf(fmaxf(gv1, -1.0f), 1.0f));  // in [-1,1]
      float s1s = fxp_rnd(hsig(gv1));
      float s1 = (lane & 8) ? s1s : s1t;
      float p0 = __shfl_xor(s0, 8);
      float p1 = __shfl_xor(s1, 8);
      float iv = writer ? s0 : p0;
      float fv = writer ? p0 : s0;
      float gv = writer ? s1 : p1;
      float ov = writer ? p1 : s1;
      float cn = fxp(fv * c_st[r] + iv * gv);
      c_st[r] = cn;
      float hn = fxp_rnd(ov * fminf(fmaxf(cn, -1.0f), 1.0f));  // in [-1,1]
      h_last[r] = hn;
      // deposit ENCODED h (m = h*256+256, tag bit15 = epub) into the
      // per-wave LDS tile (2 lanes/bank, free). hn*256 is an exact integer.
      if (writer) {
        unsigned short es =
            (unsigned short)(((int)(hn * 256.0f) + 256) | epub);
        ts[(lrow + r) * 8 + c7] = __builtin_bit_cast(_Float16, es);
      }
    }
    // wave-local: wait for the tile, lanes 0-15 transpose-read (b64, 16
    // distinct bank-pairs) and issue 16 contiguous 8B agent stores (two
    // lanes = one 16B run per row). Each 8B store self-validates via tags.
    asm volatile("s_waitcnt lgkmcnt(0)" ::: "memory");
    if (lane < 16) {
      u64 hv = *(const u64*)(ts + (lane >> 1) * 8 + ((lane & 1) << 2));
      __hip_atomic_store(
          (u64*)&hbw[(lane >> 1) * 1024 + jbase + ((lane & 1) << 2)], hv,
          __ATOMIC_RELAXED, __HIP_MEMORY_SCOPE_AGENT);
    }
    // out stores: plain cached, off the sync path entirely
    if (writer) {
#pragma unroll
      for (int r = 0; r < 4; r++)
        out[((size_t)((grp << 3) + lrow + r) * 256 + t) * 1024 + jc] =
            h_last[r];
    }
  }

  if (writer) {
#pragma unroll
    for (int r = 0; r < 4; r++) {
      out[16777216 + (size_t)((grp << 3) + lrow + r) * 1024 + jc] = h_last[r];
      out[16777216 + 65536 + (size_t)((grp << 3) + lrow + r) * 1024 + jc] =
          c_st[r];
    }
  }
}

// ---------------------------------------------------------------------------
extern "C" void kernel_launch(void* const* d_in, const int* in_sizes, int n_in,
                              void* d_out, int out_size, void* d_ws,
                              size_t ws_size, hipStream_t stream) {
  const float* x    = (const float*)d_in[0];
  const float* w_ih = (const float*)d_in[1];
  const float* w_hh = (const float*)d_in[2];
  const float* b_ih = (const float*)d_in[3];
  const float* b_hh = (const float*)d_in[4];
  const float* h0   = (const float*)d_in[5];
  const float* c0   = (const float*)d_in[6];
  float* out = (float*)d_out;

  // workspace layout (bytes); total ~156.3 MB
  char* ws = (char*)d_ws;
  unsigned* flags = (unsigned*)ws;                    // unused in R17
  _Float16* hbuf  = (_Float16*)(ws + 2048);           // 8*2*8*1024*2 = 256 KB
  _Float16* whhq  = (_Float16*)(ws + 264192);         // 8 MB
  _Float16* wihq  = (_Float16*)(ws + 8652800);        // 4 MB
  float*    bihq  = (float*)(ws + 12847104);          // 16 KB
  float*    bhhq  = (float*)(ws + 12863488);          // 16 KB
  _Float16* xq    = (_Float16*)(ws + 12879872);       // 16 MB
  _Float16* gxb   = (_Float16*)(ws + 29657088);       // 128 MB packed

  // Poison hbuf with 0x80 bytes: every half gets bit15=1 (tag=1), so t=1
  // (expected tag 0) cannot validate stale slot-1 memory. qh0 then writes
  // slot 0 with encoded tag-0 h0.
  hipMemsetAsync(hbuf, 0x80, 262144, stream);
  qf16_kernel<<<dim3(4096), 256, 0, stream>>>(w_hh, whhq, 4194304 / 4);
  qf16_kernel<<<dim3(2048), 256, 0, stream>>>(w_ih, wihq, 2097152 / 4);
  qx_kernel<<<dim3(8192), 256, 0, stream>>>(x, xq);
  qh0_kernel<<<dim3(64), 256, 0, stream>>>(h0, hbuf);
  qf32_kernel<<<dim3(4), 256, 0, stream>>>(b_ih, bihq, 4096 / 4);
  qf32_kernel<<<dim3(4), 256, 0, stream>>>(b_hh, bhhq, 4096 / 4);
  gemm_gx_kernel<<<dim3(128, 32), 256, 0, stream>>>(xq, wihq, bihq, gxb);
  lstm_kernel<<<dim3(256), 256, 0, stream>>>(whhq, bhhq, gxb, c0, hbuf, out,
                                             flags);
}

// Round 8
// 1390.174 us; speedup vs baseline: 1.1372x; 1.1372x over previous
//
#include <hip/hip_runtime.h>
#include <stdint.h>

// ---------------------------------------------------------------------------
// FixedPointLSTM (B=64, T=256, I=512, H=1024), fixed-point Q8.8 with hard
// activations. All fxp grid values are exactly representable in fp16; fp16
// MFMA with fp32 accumulate matches the numpy reference to ~1 grid step.
//
// R18: hardware-overlapped dual residency. Ledger: R11 FAIL, R12 -30us,
// R13 +7us (kept, 862us), R14 -315us, R15 0, R16 -174us, R17 -511us.
// Key diagnostic: R16's per-ROUND time was 2.02us (1036/512) vs R13's
// 3.37us -- a group's sync round shrinks ~40% when its poll overlaps other
// work. R16 lost by serializing two rounds per timestep in program order
// and doubling staging per block. R18 gets the overlap from the CU
// scheduler instead (m114: co-resident waves overlap stalls):
//  * 512 blocks = 8 groups x 64 ranks; rank owns 16 cols x 4 gates
//    (64 W_hh rows -> B-frags 32 x h8 = 128 VGPR, half of R13).
//  * __launch_bounds__(256,2), no a255 pin -> 2 blocks/CU, all 512
//    co-resident; when one block's w0 polls, the other block computes.
//  * Per-block protocol is R13 VERBATIM (gx prefetch -> w0 narrow flag poll
//    -> barrier -> R13 stage -> barrier -> MFMA -> gates -> per-wave
//    coalesced publish -> drain barrier -> flag -> out stores).
//  * Wave w = one 16-wide tile packing 2 gates x 8 cols (R13's g01
//    interleave): waves 0-1 = {i,f} cols lo/hi, waves 2-3 = {g,o}.
//    i,f cross to g,o owners via a 512B LDS xch (u32/cell, 2-way banks,
//    one extra barrier). Waves 2-3 writer lanes own c/h state.
//  * Arithmetic exact: products on the 1/65536 grid, |sums| < 2^24 ->
//    fp32 accumulation is exact in any order -> bitwise-identical gh.
// gx repacked [t][grp][rank64][fam][w01][g01][c7][q][r] fp16 (same 128 MB).
// Flags [8][64] u32 = 2 KB.
// ---------------------------------------------------------------------------

typedef _Float16 h8 __attribute__((ext_vector_type(8)));
typedef _Float16 h4 __attribute__((ext_vector_type(4)));
typedef float f4 __attribute__((ext_vector_type(4)));
typedef unsigned long long u64;

#define MFMA16(a, b, c) __builtin_amdgcn_mfma_f32_16x16x32_f16(a, b, c, 0, 0, 0)

__device__ __forceinline__ float fxp(float x) {
  float q = rintf(x * 256.0f) * 0.00390625f;
  return fminf(fmaxf(q, -128.0f), 127.99609375f);
}

// round-only: for values provably in [-128, 127.996] the clamp is a no-op.
__device__ __forceinline__ float fxp_rnd(float x) {
  return rintf(x * 256.0f) * 0.00390625f;
}

__device__ __forceinline__ float hsig(float x) {
  return fminf(fmaxf(x / 6.0f + 0.5f, 0.0f), 1.0f);  // IEEE div to match np
}

// ---- quantize fp32 -> fxp grid, store fp16 ---------------------------------
__global__ void qf16_kernel(const float* __restrict__ in,
                            _Float16* __restrict__ out, int n4) {
  int i = blockIdx.x * 256 + threadIdx.x;
  if (i < n4) {
    float4 v = ((const float4*)in)[i];
    h4 o;
    o[0] = (_Float16)fxp(v.x); o[1] = (_Float16)fxp(v.y);
    o[2] = (_Float16)fxp(v.z); o[3] = (_Float16)fxp(v.w);
    ((h4*)out)[i] = o;
  }
}

// quantize + transpose x: in [64][256][512] -> rows m = t*64+b, [16384][512]
__global__ void qx_kernel(const float* __restrict__ in,
                          _Float16* __restrict__ out) {
  int i4 = blockIdx.x * 256 + threadIdx.x;  // over 16384*128 float4s
  int col4 = i4 & 127;
  int row = i4 >> 7;  // b*256 + t
  int b = row >> 8, tt = row & 255;
  float4 v = ((const float4*)in)[i4];
  h4 o;
  o[0] = (_Float16)fxp(v.x); o[1] = (_Float16)fxp(v.y);
  o[2] = (_Float16)fxp(v.z); o[3] = (_Float16)fxp(v.w);
  ((h4*)out)[(size_t)((tt << 6) + b) * 128 + col4] = o;
}

__global__ void qf32_kernel(const float* __restrict__ in,
                            float* __restrict__ out, int n4) {
  int i = blockIdx.x * 256 + threadIdx.x;
  if (i < n4) {
    float4 v = ((const float4*)in)[i];
    float4 o;
    o.x = fxp(v.x); o.y = fxp(v.y); o.z = fxp(v.z); o.w = fxp(v.w);
    ((float4*)out)[i] = o;
  }
}

// h0 -> hbuf buffer 0, layout [grp=8][buf=2][row=8][1024] fp16
__global__ void qh0_kernel(const float* __restrict__ in,
                           _Float16* __restrict__ hbuf) {
  int i = blockIdx.x * 256 + threadIdx.x;  // over 64*1024/4
  int col4 = i & 255, b = i >> 8;
  float4 v = ((const float4*)in)[i];
  h4 o;
  o[0] = (_Float16)fxp(v.x); o[1] = (_Float16)fxp(v.y);
  o[2] = (_Float16)fxp(v.z); o[3] = (_Float16)fxp(v.w);
  *(h4*)(hbuf + (size_t)(b >> 3) * 16384 + (b & 7) * 1024 + col4 * 4) = o;
}

// ---- async global->LDS helper (width 16B; LDS dest = wave-uniform base) ----
__device__ __forceinline__ void gload_lds16(const _Float16* g, _Float16* l) {
  __builtin_amdgcn_global_load_lds(
      (const __attribute__((address_space(1))) uint32_t*)g,
      (__attribute__((address_space(3))) uint32_t*)l, 16, 0, 0);
}

// ---------------------------------------------------------------------------
// gx = fxp(x_q @ w_ih_q^T + b_ih_q), packed
//   [t 256][grp 8][rank 64][fam 2][w01 2][g01 2][c7 8][q 2][r 4] fp16
// (128 MB). Consumer wave w = fam*2+w01, lane (g01,c7,qq) h4-loads its 4 rows.
// ---------------------------------------------------------------------------
__global__ __launch_bounds__(256) void gemm_gx_kernel(
    const _Float16* __restrict__ Xq,   // [16384][512], m = t*64+b
    const _Float16* __restrict__ Wih,  // [4096][512]
    const float* __restrict__ bih,     // [4096]
    _Float16* __restrict__ gx)         // packed, see above
{
  __shared__ _Float16 As[128 * 32];
  __shared__ _Float16 Bs[128 * 32];
  const int tid = threadIdx.x;
  const int lane = tid & 63;
  const int w = tid >> 6;
  const int wm = (w >> 1) * 64;
  const int wn = (w & 1) * 64;
  const int m0 = blockIdx.x * 128;
  const int n0 = blockIdx.y * 128;
  const int cl = lane & 15, q = lane >> 4;

  f4 acc[4][4] = {};

  for (int k0 = 0; k0 < 512; k0 += 32) {
#pragma unroll
    for (int i = 0; i < 2; i++) {
      int idx = i * 256 + tid;
      int row = idx >> 2;
      int kc = (idx & 3) << 3;
      int wbase = (i * 256 + (tid & 192)) << 3;  // wave-uniform LDS base
      gload_lds16(Xq + (size_t)(m0 + row) * 512 + k0 + kc, As + wbase);
      gload_lds16(Wih + (size_t)(n0 + row) * 512 + k0 + kc, Bs + wbase);
    }
    __syncthreads();
    h8 af[4], bf[4];
#pragma unroll
    for (int mt = 0; mt < 4; mt++)
      af[mt] = *(const h8*)(As + (wm + mt * 16 + cl) * 32 + q * 8);
#pragma unroll
    for (int nt = 0; nt < 4; nt++)
      bf[nt] = *(const h8*)(Bs + (wn + nt * 16 + cl) * 32 + q * 8);
#pragma unroll
    for (int mt = 0; mt < 4; mt++)
#pragma unroll
      for (int nt = 0; nt < 4; nt++)
        acc[mt][nt] = MFMA16(af[mt], bf[nt], acc[mt][nt]);
    __syncthreads();
  }

#pragma unroll
  for (int nt = 0; nt < 4; nt++) {
    const int n = n0 + wn + nt * 16 + cl;  // gate-col 0..4095
    const float bv = bih[n];
    const int wg = n >> 10;                 // gate 0..3
    const int fam = wg >> 1, gg1 = wg & 1;
    const int j = n & 1023;
    const int rank = j >> 4, w01 = (j >> 3) & 1, c7 = j & 7;
#pragma unroll
    for (int mt = 0; mt < 4; mt++) {
      const int m = m0 + wm + mt * 16 + q * 4;  // 4-aligned
      const int b = m & 63, tt = m >> 6;
      const int grp = b >> 3, qv = (b >> 2) & 1;
      h4 pk;
#pragma unroll
      for (int r = 0; r < 4; r++) pk[r] = (_Float16)fxp(acc[mt][nt][r] + bv);
      const size_t off =
          (((((((size_t)tt * 8 + grp) * 64 + rank) * 2 + fam) * 2 + w01) * 2 +
            gg1) * 8 + c7) * 8 + (qv << 2);
      *(h4*)(gx + off) = pk;
    }
  }
}

// ---------------------------------------------------------------------------
// Persistent recurrence. 512 blocks x 256 threads, 2 blocks/CU (the overlap
// engine). Block = (grp = blockIdx&7, rank = blockIdx>>3, 64 ranks); group
// owns batch rows 8g..8g+7; rank owns h-cols rank*16..+15 x 4 gates.
// Wave w: one 16-wide B-tile = gates {fam*2, fam*2+1} x cols
// j0+w01*8..+8 (g01-interleaved, R13 packing). Per step: R13 protocol.
// ---------------------------------------------------------------------------
__global__ __launch_bounds__(256, 2) void lstm_kernel(
    const _Float16* __restrict__ Whh,  // [4096][1024] quantized
    const float* __restrict__ bhh,     // [4096] quantized
    const _Float16* __restrict__ gx,   // packed, see gemm
    const float* __restrict__ c0,      // [64][1024]
    _Float16* __restrict__ hbuf,       // [8][2][8][1024] fp16
    float* __restrict__ out,           // [64][256][1024] ++ h_n ++ c_n
    unsigned* __restrict__ flags)      // [8][64]
{
  const int tid = threadIdx.x;
  const int lane = tid & 63;
  const int w = tid >> 6;
  const int w01 = w & 1, fam = w >> 1;
  const int cl = lane & 15, q = lane >> 4, qq = q & 1;
  const int c7 = lane & 7;
  const int g01 = (lane >> 3) & 1;

  const int grp = blockIdx.x & 7;    // batch octet
  const int rank = blockIdx.x >> 3;  // 16-column slice owner, 0..63
  const int j0 = rank << 4;

  // persistent B fragment: ONE tile (2 gates x 8 cols) x 32 k-steps = 128 regs
  const int brow = (((fam << 1) | g01) << 10) + j0 + (w01 << 3) + c7;
  h8 B[32];
#pragma unroll
  for (int kt = 0; kt < 32; kt++)
    B[kt] = *(const h8*)(Whh + (size_t)brow * 1024 + (kt << 5) + (q << 3));
  const float bh = bhh[brow];

  const int jc = j0 + (w01 << 3) + c7;  // h column for writer lanes
  const int lrow = qq << 2;             // local batch row base (q<2 lanes)
  const bool writer = ((lane & 8) == 0) && (q < 2);
  const bool cellw = writer && (fam == 1);  // waves 2-3 writers own c/h

  float c_st[4], h_last[4];
#pragma unroll
  for (int r = 0; r < 4; r++) {
    c_st[r] = c0[((grp << 3) + lrow + r) * 1024 + jc];  // used iff cellw
    h_last[r] = 0.0f;
  }

  // LDS: hs [8][1032] (R13 pad, conflict-free frag reads) + per-wave 64-half
  // publication tiles (waves 2-3 use theirs) + xch[128] u32 {i,f} pairs.
  __shared__ alignas(16) _Float16 hs[8 * 1032 + 4 * 64];
  __shared__ unsigned xch[128];
  const int arow = cl & 7;
  const u64* hb64 = (const u64*)hbuf;  // [grp: 4096][buf: 2048] u64s
  const size_t lsrc = (size_t)grp * 4096 + (size_t)((tid >> 5) << 8) + (tid & 31);
  _Float16* ldst = hs + (tid >> 5) * 1032 + ((tid & 31) << 2);
  _Float16* ts = hs + 8 * 1032 + w * 64;  // per-wave [8 rows][8 cols]

  unsigned* myflag = flags + (grp << 6) + rank;
  const u64* f2 = (const u64*)(flags + (grp << 6));  // 32 u64 per group

  for (int t = 0; t < 256; t++) {
    // gx fragment: 8B/lane, q>=2 duplicates q<2 (broadcast-coalesced)
    const h4 gxv = *(const h4*)(
        gx + (((((((size_t)t * 8 + grp) * 64 + rank) * 2 + fam) * 2 + w01) * 2 +
               g01) * 8 + c7) * 8 + (qq << 2));

    if (t) {
      if (w == 0) {
        const unsigned tt = (unsigned)t;
        int it = 0;
        for (;;) {
          u64 v = __hip_atomic_load(&f2[lane & 31], __ATOMIC_RELAXED,
                                    __HIP_MEMORY_SCOPE_AGENT);
          bool ok = ((unsigned)v >= tt) && ((unsigned)(v >> 32) >= tt);
          if (__ballot(ok) == ~0ull) break;
          if (++it > (1 << 14)) break;  // hang insurance (loudly wrong)
          __builtin_amdgcn_s_sleep(1);
        }
      }
      __syncthreads();  // B
    }

    // ---- stage h_t (16KB): 8 coalesced 8B agent loads -> ds_write_b64 ----
    {
      const u64* src = hb64 + lsrc + (size_t)(t & 1) * 2048;
      u64 v0 = __hip_atomic_load(src + 0 * 32, __ATOMIC_RELAXED, __HIP_MEMORY_SCOPE_AGENT);
      u64 v1 = __hip_atomic_load(src + 1 * 32, __ATOMIC_RELAXED, __HIP_MEMORY_SCOPE_AGENT);
      u64 v2 = __hip_atomic_load(src + 2 * 32, __ATOMIC_RELAXED, __HIP_MEMORY_SCOPE_AGENT);
      u64 v3 = __hip_atomic_load(src + 3 * 32, __ATOMIC_RELAXED, __HIP_MEMORY_SCOPE_AGENT);
      u64 v4 = __hip_atomic_load(src + 4 * 32, __ATOMIC_RELAXED, __HIP_MEMORY_SCOPE_AGENT);
      u64 v5 = __hip_atomic_load(src + 5 * 32, __ATOMIC_RELAXED, __HIP_MEMORY_SCOPE_AGENT);
      u64 v6 = __hip_atomic_load(src + 6 * 32, __ATOMIC_RELAXED, __HIP_MEMORY_SCOPE_AGENT);
      u64 v7 = __hip_atomic_load(src + 7 * 32, __ATOMIC_RELAXED, __HIP_MEMORY_SCOPE_AGENT);
      *(u64*)(ldst + 0 * 128) = v0;
      *(u64*)(ldst + 1 * 128) = v1;
      *(u64*)(ldst + 2 * 128) = v2;
      *(u64*)(ldst + 3 * 128) = v3;
      *(u64*)(ldst + 4 * 128) = v4;
      *(u64*)(ldst + 5 * 128) = v5;
      *(u64*)(ldst + 6 * 128) = v6;
      *(u64*)(ldst + 7 * 128) = v7;
    }
    __syncthreads();  // C

    // ---- MFMA: one gate-pair tile over K=1024 (even/odd chains) ----------
    f4 a0 = {}, a1 = {};
#pragma unroll
    for (int kt = 0; kt < 32; kt++) {
      h8 av = *(const h8*)(hs + arow * 1032 + (kt << 5) + (q << 3));
      if (kt & 1) a1 = MFMA16(av, B[kt], a1);
      else        a0 = MFMA16(av, B[kt], a0);
    }
    f4 g = a0 + a1;

    // ---- gates: own-gate activation + intra-wave pair shfl ---------------
    float g_own[4], o_own[4];
#pragma unroll
    for (int r = 0; r < 4; r++) {
      float gv = fxp((float)gxv[r] + fxp(g[r] + bh));
      float s;
      if (fam == 0) {
        s = fxp_rnd(hsig(gv));  // i (g01=0) or f (g01=1)
      } else {
        float st = fxp_rnd(fminf(fmaxf(gv, -1.0f), 1.0f));  // g
        float ss = fxp_rnd(hsig(gv));                       // o
        s = (lane & 8) ? ss : st;
      }
      float p = __shfl_xor(s, 8);
      if (fam == 0) {
        if (writer) {  // s = i, p = f -> pack to xch[cell]
          unsigned lo = __builtin_bit_cast(unsigned short, (_Float16)s);
          unsigned hi = __builtin_bit_cast(unsigned short, (_Float16)p);
          xch[(lrow + r) * 16 + (w01 << 3) + c7] = lo | (hi << 16);
        }
      } else {
        g_own[r] = s;  // g (writer lanes have lane&8==0 -> hardtanh)
        o_own[r] = p;  // o from partner
      }
    }
    __syncthreads();  // D: xch visible to waves 2-3

    // ---- c/h update (waves 2-3 writer lanes), deposit to ts --------------
    _Float16* hbw = hbuf + (size_t)grp * 16384 + ((t + 1) & 1) * 8192;
    if (cellw) {
#pragma unroll
      for (int r = 0; r < 4; r++) {
        unsigned px = xch[(lrow + r) * 16 + (w01 << 3) + c7];
        float iv = (float)__builtin_bit_cast(_Float16, (unsigned short)px);
        float fv =
            (float)__builtin_bit_cast(_Float16, (unsigned short)(px >> 16));
        float cn = fxp(fv * c_st[r] + iv * g_own[r]);
        c_st[r] = cn;
        float hn = fxp_rnd(o_own[r] * fminf(fmaxf(cn, -1.0f), 1.0f));
        h_last[r] = hn;
        ts[(lrow + r) * 8 + c7] = (_Float16)hn;  // 2 lanes/bank, free
      }
    }
    // wave-local (waves 2-3): wait tile, lanes 0-15 transpose-read b64 and
    // issue 16 contiguous 8B agent stores (two lanes = 16B run per row).
    asm volatile("s_waitcnt lgkmcnt(0)" ::: "memory");
    if (fam == 1 && lane < 16) {
      u64 hv = *(const u64*)(ts + (lane >> 1) * 8 + ((lane & 1) << 2));
      __hip_atomic_store(
          (u64*)&hbw[(lane >> 1) * 1024 + j0 + (w01 << 3) + ((lane & 1) << 2)],
          hv, __ATOMIC_RELAXED, __HIP_MEMORY_SCOPE_AGENT);
    }
    __syncthreads();  // A: drains the h stores
    if (tid == 0)
      __hip_atomic_store(myflag, (unsigned)(t + 1), __ATOMIC_RELAXED,
                         __HIP_MEMORY_SCOPE_AGENT);
    // out stores after the flag: plain cached, off the sync path
    if (cellw) {
#pragma unroll
      for (int r = 0; r < 4; r++)
        out[((size_t)((grp << 3) + lrow + r) * 256 + t) * 1024 + jc] =
            h_last[r];
    }
  }

  if (cellw) {
#pragma unroll
    for (int r = 0; r < 4; r++) {
      out[16777216 + (size_t)((grp << 3) + lrow + r) * 1024 + jc] = h_last[r];
      out[16777216 + 65536 + (size_t)((grp << 3) + lrow + r) * 1024 + jc] =
          c_st[r];
    }
  }
}

// ---------------------------------------------------------------------------
extern "C" void kernel_launch(void* const* d_in, const int* in_sizes, int n_in,
                              void* d_out, int out_size, void* d_ws,
                              size_t ws_size, hipStream_t stream) {
  const float* x    = (const float*)d_in[0];
  const float* w_ih = (const float*)d_in[1];
  const float* w_hh = (const float*)d_in[2];
  const float* b_ih = (const float*)d_in[3];
  const float* b_hh = (const float*)d_in[4];
  const float* h0   = (const float*)d_in[5];
  const float* c0   = (const float*)d_in[6];
  float* out = (float*)d_out;

  // workspace layout (bytes); total ~156.3 MB
  char* ws = (char*)d_ws;
  unsigned* flags = (unsigned*)ws;                    // [8][64] u32 = 2 KB
  _Float16* hbuf  = (_Float16*)(ws + 2048);           // 8*2*8*1024*2 = 256 KB
  _Float16* whhq  = (_Float16*)(ws + 264192);         // 8 MB
  _Float16* wihq  = (_Float16*)(ws + 8652800);        // 4 MB
  float*    bihq  = (float*)(ws + 12847104);          // 16 KB
  float*    bhhq  = (float*)(ws + 12863488);          // 16 KB
  _Float16* xq    = (_Float16*)(ws + 12879872);       // 16 MB
  _Float16* gxb   = (_Float16*)(ws + 29657088);       // 128 MB packed

  hipMemsetAsync(flags, 0, 2048, stream);
  qf16_kernel<<<dim3(4096), 256, 0, stream>>>(w_hh, whhq, 4194304 / 4);
  qf16_kernel<<<dim3(2048), 256, 0, stream>>>(w_ih, wihq, 2097152 / 4);
  qx_kernel<<<dim3(8192), 256, 0, stream>>>(x, xq);
  qh0_kernel<<<dim3(64), 256, 0, stream>>>(h0, hbuf);
  qf32_kernel<<<dim3(4), 256, 0, stream>>>(b_ih, bihq, 4096 / 4);
  qf32_kernel<<<dim3(4), 256, 0, stream>>>(b_hh, bhhq, 4096 / 4);
  gemm_gx_kernel<<<dim3(128, 32), 256, 0, stream>>>(xq, wihq, bihq, gxb);
  lstm_kernel<<<dim3(512), 256, 0, stream>>>(whhq, bhhq, gxb, c0, hbuf, out,
                                             flags);
}

// Round 9
// 1075.575 us; speedup vs baseline: 1.4698x; 1.2925x over previous
//
#include <hip/hip_runtime.h>
#include <stdint.h>

// ---------------------------------------------------------------------------
// FixedPointLSTM (B=64, T=256, I=512, H=1024), fixed-point Q8.8 with hard
// activations. All fxp grid values are exactly representable in fp16; fp16
// MFMA with fp32 accumulate matches the numpy reference to ~1 grid step.
//
// R19 = R13 (verified 862 us lstm / 1063 us total) + FUSED input projection.
// Ledger: R11 FAIL, R12 -30, R13 +7 (kept), R14 -315, R15 0, R16 -174,
// R17 -511, R18 -416. Eight sync-structure attempts lost; R13's protocol is
// the latency floor. R19 leaves the recurrence protocol VERBATIM and instead
// deletes the ~200us serial gemm_gx dispatch by computing gx inside the
// recurrence's 65% stall time:
//  * W_ih fragments persistent in registers: 2 tiles x 16 k-steps x h8 =
//    128 regs (on top of Whh's 256; unified VGPR/AGPR file, ~430 total).
//  * x_q[t] (8 rows x 512 = 8KB) staged into LDS xs[8][520] with the exact
//    verified staging pattern (same coalescing, same bank class; stride 520
//    == 1032 mod-32 bank offset). Prefetch issued where R13 issued the gx
//    prefetch (overlaps the poll), ds_write with the h stage, drains at C.
//  * accx = single ascending K-chain (kt=0..15) -> BITWISE identical to the
//    deleted gemm's acc; gxv = fxp(accx + bih) replaces the gx load.
// Removes: gemm_gx kernel, 128MB gx write + 128MB gx read HBM traffic.
// ---------------------------------------------------------------------------

typedef _Float16 h8 __attribute__((ext_vector_type(8)));
typedef _Float16 h4 __attribute__((ext_vector_type(4)));
typedef float f4 __attribute__((ext_vector_type(4)));
typedef unsigned long long u64;

#define MFMA16(a, b, c) __builtin_amdgcn_mfma_f32_16x16x32_f16(a, b, c, 0, 0, 0)

__device__ __forceinline__ float fxp(float x) {
  float q = rintf(x * 256.0f) * 0.00390625f;
  return fminf(fmaxf(q, -128.0f), 127.99609375f);
}

// round-only: for values provably in [-128, 127.996] the clamp is a no-op.
__device__ __forceinline__ float fxp_rnd(float x) {
  return rintf(x * 256.0f) * 0.00390625f;
}

__device__ __forceinline__ float hsig(float x) {
  return fminf(fmaxf(x / 6.0f + 0.5f, 0.0f), 1.0f);  // IEEE div to match np
}

// ---- quantize fp32 -> fxp grid, store fp16 ---------------------------------
__global__ void qf16_kernel(const float* __restrict__ in,
                            _Float16* __restrict__ out, int n4) {
  int i = blockIdx.x * 256 + threadIdx.x;
  if (i < n4) {
    float4 v = ((const float4*)in)[i];
    h4 o;
    o[0] = (_Float16)fxp(v.x); o[1] = (_Float16)fxp(v.y);
    o[2] = (_Float16)fxp(v.z); o[3] = (_Float16)fxp(v.w);
    ((h4*)out)[i] = o;
  }
}

// quantize + transpose x: in [64][256][512] -> rows m = t*64+b, [16384][512]
__global__ void qx_kernel(const float* __restrict__ in,
                          _Float16* __restrict__ out) {
  int i4 = blockIdx.x * 256 + threadIdx.x;  // over 16384*128 float4s
  int col4 = i4 & 127;
  int row = i4 >> 7;  // b*256 + t
  int b = row >> 8, tt = row & 255;
  float4 v = ((const float4*)in)[i4];
  h4 o;
  o[0] = (_Float16)fxp(v.x); o[1] = (_Float16)fxp(v.y);
  o[2] = (_Float16)fxp(v.z); o[3] = (_Float16)fxp(v.w);
  ((h4*)out)[(size_t)((tt << 6) + b) * 128 + col4] = o;
}

__global__ void qf32_kernel(const float* __restrict__ in,
                            float* __restrict__ out, int n4) {
  int i = blockIdx.x * 256 + threadIdx.x;
  if (i < n4) {
    float4 v = ((const float4*)in)[i];
    float4 o;
    o.x = fxp(v.x); o.y = fxp(v.y); o.z = fxp(v.z); o.w = fxp(v.w);
    ((float4*)out)[i] = o;
  }
}

// h0 -> hbuf buffer 0, layout [grp=8][buf=2][row=8][1024] fp16
__global__ void qh0_kernel(const float* __restrict__ in,
                           _Float16* __restrict__ hbuf) {
  int i = blockIdx.x * 256 + threadIdx.x;  // over 64*1024/4
  int col4 = i & 255, b = i >> 8;
  float4 v = ((const float4*)in)[i];
  h4 o;
  o[0] = (_Float16)fxp(v.x); o[1] = (_Float16)fxp(v.y);
  o[2] = (_Float16)fxp(v.z); o[3] = (_Float16)fxp(v.w);
  *(h4*)(hbuf + (size_t)(b >> 3) * 16384 + (b & 7) * 1024 + col4 * 4) = o;
}

// ---------------------------------------------------------------------------
// Persistent recurrence WITH fused input projection. 256 blocks x 256
// threads, a255 pin -> 1 block/CU. Block = (grp = blockIdx&7, rank =
// blockIdx>>3); group owns batch rows 8g..8g+7; rank owns h-cols
// rank*32..+31 x 4 gates (128 W_hh rows + 128 W_ih rows in regs).
// Per step (R13 protocol):
//   x[t] prefetch (4 u64/thread, coalesced; overlaps the poll) ->
//   w0 polls 32 per-block flags -> barrier B -> stage h (8x8B agent loads)
//   + ds_write h AND x -> barrier C -> MFMA (accx single chain, bitwise ==
//   old gemm; recurrence even/odd chains) -> gxv = fxp(accx+bih) -> gates
//   -> h tile publication (R13) -> barrier A (drains h) -> tid0 flag ->
//   out stores (nontemporal, off sync path).
// ---------------------------------------------------------------------------
__global__ __launch_bounds__(256, 1) void lstm_kernel(
    const _Float16* __restrict__ Whh,  // [4096][1024] quantized
    const float* __restrict__ bhh,     // [4096] quantized
    const _Float16* __restrict__ Xq,   // [16384][512], row m = t*64+b
    const _Float16* __restrict__ Wih,  // [4096][512] quantized
    const float* __restrict__ bih,     // [4096] quantized
    const float* __restrict__ c0,      // [64][1024]
    _Float16* __restrict__ hbuf,       // [8][2][8][1024] fp16
    float* __restrict__ out,           // [64][256][1024] ++ h_n ++ c_n
    unsigned* __restrict__ flags)      // [8][32]
{
  // Residency pin: force total regs/wave > 256 -> 1 wave/SIMD -> 1 block/CU.
  asm volatile("v_accvgpr_write_b32 a255, 0" ::: "a255");

  const int tid = threadIdx.x;
  const int lane = tid & 63;
  const int w = tid >> 6;
  const int cl = lane & 15, q = lane >> 4;
  const int g01 = (lane >> 3) & 1;
  const int c7 = lane & 7;

  const int grp = blockIdx.x & 7;    // batch octet
  const int rank = blockIdx.x >> 3;  // 32-column slice owner

  const int jbase = (rank << 5) + (w << 3);         // block/wave col base
  const int row0 = (g01 << 10) + jbase + c7;        // gates i/f
  const int row1 = ((g01 + 2) << 10) + jbase + c7;  // gates g/o

  // persistent B fragments: Whh 2 tiles x 32 k-steps = 256 regs,
  // Wih 2 tiles x 16 k-steps = 128 regs (unified VGPR/AGPR file).
  h8 B0[32], B1[32];
#pragma unroll
  for (int kt = 0; kt < 32; kt++) {
    B0[kt] = *(const h8*)(Whh + (size_t)row0 * 1024 + (kt << 5) + (q << 3));
    B1[kt] = *(const h8*)(Whh + (size_t)row1 * 1024 + (kt << 5) + (q << 3));
  }
  h8 C0[16], C1[16];
#pragma unroll
  for (int kt = 0; kt < 16; kt++) {
    C0[kt] = *(const h8*)(Wih + (size_t)row0 * 512 + (kt << 5) + (q << 3));
    C1[kt] = *(const h8*)(Wih + (size_t)row1 * 512 + (kt << 5) + (q << 3));
  }
  const float bh0 = bhh[row0], bh1 = bhh[row1];
  const float bx0 = bih[row0], bx1 = bih[row1];
  const int jc = jbase + c7;        // h column 0..1023
  const int lrow = ((q & 1) << 2);  // local batch row base (valid q<2)
  const bool writer = ((lane & 8) == 0) && (q < 2);

  float c_st[4], h_last[4];
#pragma unroll
  for (int r = 0; r < 4; r++) {
    c_st[r] = c0[((grp << 3) + lrow + r) * 1024 + jc];
    h_last[r] = 0.0f;
  }

  // LDS: hs [8][1032] h-stage (R6-verified pad) + per-wave publication tiles
  // + xs [8][520] x-stage (stride 520: 1040B = same mod-32 bank offset class
  // as 1032's 2064B -> identical conflict-free fragment reads).
  __shared__ alignas(16) _Float16 hs[8 * 1032 + 4 * 64];
  __shared__ alignas(16) _Float16 xs[8 * 520];
  const int arow = cl & 7;
  const u64* hb64 = (const u64*)hbuf;  // [grp: 4096][buf: 2048] u64s
  const u64* xq64 = (const u64*)Xq;    // [16384][128] u64s
  const int srow = tid >> 5, sc = tid & 31;
  const size_t lsrc = (size_t)grp * 4096 + (size_t)(srow << 8) + sc;
  _Float16* ldst = hs + srow * 1032 + (sc << 2);
  _Float16* xdst = xs + srow * 520 + (sc << 2);
  _Float16* ts = hs + 8 * 1032 + w * 64;  // per-wave [8 rows][8 cols] tile

  unsigned* myflag = flags + (grp << 5) + rank;
  const u64* f2 = (const u64*)(flags + (grp << 5));  // 16 u64 per group

  for (int t = 0; t < 256; t++) {
    // prefetch x_q[t] slice: 4 coalesced u64 loads/thread (overlaps poll)
    const u64* xsrc = xq64 + ((size_t)(t << 6) + (grp << 3) + srow) * 128 + sc;
    u64 x0 = xsrc[0], x1 = xsrc[32], x2 = xsrc[64], x3 = xsrc[96];

    if (t) {
      if (w == 0) {
        const unsigned tt = (unsigned)t;
        int it = 0;
        for (;;) {
          u64 v = __hip_atomic_load(&f2[lane & 15], __ATOMIC_RELAXED,
                                    __HIP_MEMORY_SCOPE_AGENT);
          bool ok = ((unsigned)v >= tt) && ((unsigned)(v >> 32) >= tt);
          if (__ballot(ok) == ~0ull) break;
          if (++it > (1 << 14)) break;  // hang insurance (loudly wrong)
          __builtin_amdgcn_s_sleep(1);
        }
      }
      __syncthreads();  // B
    }

    // ---- stage h_t (16KB) + x_t (8KB): agent loads -> ds_write_b64 -------
    {
      const u64* src = hb64 + lsrc + (size_t)(t & 1) * 2048;
      u64 v0 = __hip_atomic_load(src + 0 * 32, __ATOMIC_RELAXED, __HIP_MEMORY_SCOPE_AGENT);
      u64 v1 = __hip_atomic_load(src + 1 * 32, __ATOMIC_RELAXED, __HIP_MEMORY_SCOPE_AGENT);
      u64 v2 = __hip_atomic_load(src + 2 * 32, __ATOMIC_RELAXED, __HIP_MEMORY_SCOPE_AGENT);
      u64 v3 = __hip_atomic_load(src + 3 * 32, __ATOMIC_RELAXED, __HIP_MEMORY_SCOPE_AGENT);
      u64 v4 = __hip_atomic_load(src + 4 * 32, __ATOMIC_RELAXED, __HIP_MEMORY_SCOPE_AGENT);
      u64 v5 = __hip_atomic_load(src + 5 * 32, __ATOMIC_RELAXED, __HIP_MEMORY_SCOPE_AGENT);
      u64 v6 = __hip_atomic_load(src + 6 * 32, __ATOMIC_RELAXED, __HIP_MEMORY_SCOPE_AGENT);
      u64 v7 = __hip_atomic_load(src + 7 * 32, __ATOMIC_RELAXED, __HIP_MEMORY_SCOPE_AGENT);
      *(u64*)(ldst + 0 * 128) = v0;
      *(u64*)(ldst + 1 * 128) = v1;
      *(u64*)(ldst + 2 * 128) = v2;
      *(u64*)(ldst + 3 * 128) = v3;
      *(u64*)(ldst + 4 * 128) = v4;
      *(u64*)(ldst + 5 * 128) = v5;
      *(u64*)(ldst + 6 * 128) = v6;
      *(u64*)(ldst + 7 * 128) = v7;
      *(u64*)(xdst + 0 * 128) = x0;
      *(u64*)(xdst + 1 * 128) = x1;
      *(u64*)(xdst + 2 * 128) = x2;
      *(u64*)(xdst + 3 * 128) = x3;
    }
    __syncthreads();  // C

    // ---- MFMA: fused input projection + recurrence -----------------------
    // accx: single ascending chain (bitwise == the old gemm kernel's acc).
    f4 ax0 = {}, ax1 = {};
#pragma unroll
    for (int kt = 0; kt < 16; kt++) {
      h8 xv = *(const h8*)(xs + arow * 520 + (kt << 5) + (q << 3));
      ax0 = MFMA16(xv, C0[kt], ax0);
      ax1 = MFMA16(xv, C1[kt], ax1);
    }
    f4 a0 = {}, a1 = {}, a2 = {}, a3 = {};
#pragma unroll
    for (int kt = 0; kt < 32; kt++) {
      h8 av = *(const h8*)(hs + arow * 1032 + (kt << 5) + (q << 3));
      if (kt & 1) { a1 = MFMA16(av, B0[kt], a1); a3 = MFMA16(av, B1[kt], a3); }
      else        { a0 = MFMA16(av, B0[kt], a0); a2 = MFMA16(av, B1[kt], a2); }
    }
    f4 g0 = a0 + a1;
    f4 g1 = a2 + a3;

    _Float16* hbw = hbuf + (size_t)grp * 16384 + ((t + 1) & 1) * 8192;
#pragma unroll
    for (int r = 0; r < 4; r++) {
      float xg0 = fxp(ax0[r] + bx0);                 // gx, gate i/f
      float xg1 = fxp(ax1[r] + bx1);                 // gx, gate g/o
      float gv0 = fxp(xg0 + fxp(g0[r] + bh0));       // i or f
      float gv1 = fxp(xg1 + fxp(g1[r] + bh1));       // g or o
      float s0 = fxp_rnd(hsig(gv0));                        // in [0,1]
      float s1t = fxp_rnd(fminf(fmaxf(gv1, -1.0f), 1.0f));  // in [-1,1]
      float s1s = fxp_rnd(hsig(gv1));
      float s1 = (lane & 8) ? s1s : s1t;
      float p0 = __shfl_xor(s0, 8);
      float p1 = __shfl_xor(s1, 8);
      float iv = writer ? s0 : p0;
      float fv = writer ? p0 : s0;
      float gv = writer ? s1 : p1;
      float ov = writer ? p1 : s1;
      float cn = fxp(fv * c_st[r] + iv * gv);
      c_st[r] = cn;
      float hn = fxp_rnd(ov * fminf(fmaxf(cn, -1.0f), 1.0f));  // in [-1,1]
      h_last[r] = hn;
      // R13: deposit h into the per-wave LDS tile (2 lanes/bank, free)
      if (writer) ts[(lrow + r) * 8 + c7] = (_Float16)hn;
    }
    // wave-local: wait for the tile, lanes 0-15 transpose-read (b64) and
    // issue 16 contiguous 8B agent stores (two lanes = 16B run per row).
    asm volatile("s_waitcnt lgkmcnt(0)" ::: "memory");
    if (lane < 16) {
      u64 hv = *(const u64*)(ts + (lane >> 1) * 8 + ((lane & 1) << 2));
      __hip_atomic_store(
          (u64*)&hbw[(lane >> 1) * 1024 + jbase + ((lane & 1) << 2)], hv,
          __ATOMIC_RELAXED, __HIP_MEMORY_SCOPE_AGENT);
    }
    __syncthreads();  // A: drains the h stores (out stores not yet issued)
    if (tid == 0)
      __hip_atomic_store(myflag, (unsigned)(t + 1), __ATOMIC_RELAXED,
                         __HIP_MEMORY_SCOPE_AGENT);
    // out stores after the flag: drain overlaps the next step's poll/stage
    if (writer) {
#pragma unroll
      for (int r = 0; r < 4; r++)
        __builtin_nontemporal_store(
            h_last[r],
            &out[((size_t)((grp << 3) + lrow + r) * 256 + t) * 1024 + jc]);
    }
  }

  if (writer) {
#pragma unroll
    for (int r = 0; r < 4; r++) {
      out[16777216 + (size_t)((grp << 3) + lrow + r) * 1024 + jc] = h_last[r];
      out[16777216 + 65536 + (size_t)((grp << 3) + lrow + r) * 1024 + jc] =
          c_st[r];
    }
  }
}

// ---------------------------------------------------------------------------
extern "C" void kernel_launch(void* const* d_in, const int* in_sizes, int n_in,
                              void* d_out, int out_size, void* d_ws,
                              size_t ws_size, hipStream_t stream) {
  const float* x    = (const float*)d_in[0];
  const float* w_ih = (const float*)d_in[1];
  const float* w_hh = (const float*)d_in[2];
  const float* b_ih = (const float*)d_in[3];
  const float* b_hh = (const float*)d_in[4];
  const float* h0   = (const float*)d_in[5];
  const float* c0   = (const float*)d_in[6];
  float* out = (float*)d_out;

  // workspace layout (bytes); gxb slot now unused (fused)
  char* ws = (char*)d_ws;
  unsigned* flags = (unsigned*)ws;                    // [8][32] u32 = 1 KB
  _Float16* hbuf  = (_Float16*)(ws + 2048);           // 8*2*8*1024*2 = 256 KB
  _Float16* whhq  = (_Float16*)(ws + 264192);         // 8 MB
  _Float16* wihq  = (_Float16*)(ws + 8652800);        // 4 MB
  float*    bihq  = (float*)(ws + 12847104);          // 16 KB
  float*    bhhq  = (float*)(ws + 12863488);          // 16 KB
  _Float16* xq    = (_Float16*)(ws + 12879872);       // 16 MB

  hipMemsetAsync(flags, 0, 2048, stream);
  qf16_kernel<<<dim3(4096), 256, 0, stream>>>(w_hh, whhq, 4194304 / 4);
  qf16_kernel<<<dim3(2048), 256, 0, stream>>>(w_ih, wihq, 2097152 / 4);
  qx_kernel<<<dim3(8192), 256, 0, stream>>>(x, xq);
  qh0_kernel<<<dim3(64), 256, 0, stream>>>(h0, hbuf);
  qf32_kernel<<<dim3(4), 256, 0, stream>>>(b_ih, bihq, 4096 / 4);
  qf32_kernel<<<dim3(4), 256, 0, stream>>>(b_hh, bhhq, 4096 / 4);
  lstm_kernel<<<dim3(256), 256, 0, stream>>>(whhq, bhhq, xq, wihq, bihq, c0,
                                             hbuf, out, flags);
}

// Round 10
// 1033.920 us; speedup vs baseline: 1.5290x; 1.0403x over previous
//
#include <hip/hip_runtime.h>
#include <stdint.h>

// ---------------------------------------------------------------------------
// FixedPointLSTM (B=64, T=256, I=512, H=1024), fixed-point Q8.8 with hard
// activations. All fxp grid values are exactly representable in fp16; fp16
// MFMA with fp32 accumulate matches the numpy reference to ~1 grid step.
//
// R20 = R19 (fused input projection, 1075us total) with gx SOFTWARE-
// PIPELINED one step ahead into the idle tail.
// Ledger: R11 FAIL, R12 -30, R13 +7 (kept, 1063 total), R14 -315, R15 0,
// R16 -174, R17 -511, R18 -416, R19 ~0 (deleted 200us gemm but put its
// MFMAs on the step's critical path: lstm 862->1011).
// R20 keeps R19's fusion but moves the gx work off the critical path:
//  * xs double-buffered [2][8][520]. Tail of step t (after flag store,
//    where waves idle ~2us at the next poll): compute ax[t+1] (32 MFMA)
//    from xs[(t+1)&1], then load x[t+2] and ds_write xs[t&1]. The tail's
//    vmcnt drain means w0 enters its poll with ZERO outstanding VMEM.
//  * The critical section (barrier B -> stage h -> barrier C -> recurrence
//    MFMA -> gates -> publish -> barrier A -> flag) is R13-VERBATIM; gates
//    read pre-computed axc registers.
//  * Buffer hazards barrier-separated: tail(t-1) reads xs[b] complete
//    before barrier B(t); tail(t) writes xs[b'] occur after barrier A(t).
//  * Arithmetic identical to R19 (passing): same ascending accx chain.
// ---------------------------------------------------------------------------

typedef _Float16 h8 __attribute__((ext_vector_type(8)));
typedef _Float16 h4 __attribute__((ext_vector_type(4)));
typedef float f4 __attribute__((ext_vector_type(4)));
typedef unsigned long long u64;

#define MFMA16(a, b, c) __builtin_amdgcn_mfma_f32_16x16x32_f16(a, b, c, 0, 0, 0)

__device__ __forceinline__ float fxp(float x) {
  float q = rintf(x * 256.0f) * 0.00390625f;
  return fminf(fmaxf(q, -128.0f), 127.99609375f);
}

// round-only: for values provably in [-128, 127.996] the clamp is a no-op.
__device__ __forceinline__ float fxp_rnd(float x) {
  return rintf(x * 256.0f) * 0.00390625f;
}

__device__ __forceinline__ float hsig(float x) {
  return fminf(fmaxf(x / 6.0f + 0.5f, 0.0f), 1.0f);  // IEEE div to match np
}

// ---- quantize fp32 -> fxp grid, store fp16 ---------------------------------
__global__ void qf16_kernel(const float* __restrict__ in,
                            _Float16* __restrict__ out, int n4) {
  int i = blockIdx.x * 256 + threadIdx.x;
  if (i < n4) {
    float4 v = ((const float4*)in)[i];
    h4 o;
    o[0] = (_Float16)fxp(v.x); o[1] = (_Float16)fxp(v.y);
    o[2] = (_Float16)fxp(v.z); o[3] = (_Float16)fxp(v.w);
    ((h4*)out)[i] = o;
  }
}

// quantize + transpose x: in [64][256][512] -> rows m = t*64+b, [16384][512]
__global__ void qx_kernel(const float* __restrict__ in,
                          _Float16* __restrict__ out) {
  int i4 = blockIdx.x * 256 + threadIdx.x;  // over 16384*128 float4s
  int col4 = i4 & 127;
  int row = i4 >> 7;  // b*256 + t
  int b = row >> 8, tt = row & 255;
  float4 v = ((const float4*)in)[i4];
  h4 o;
  o[0] = (_Float16)fxp(v.x); o[1] = (_Float16)fxp(v.y);
  o[2] = (_Float16)fxp(v.z); o[3] = (_Float16)fxp(v.w);
  ((h4*)out)[(size_t)((tt << 6) + b) * 128 + col4] = o;
}

__global__ void qf32_kernel(const float* __restrict__ in,
                            float* __restrict__ out, int n4) {
  int i = blockIdx.x * 256 + threadIdx.x;
  if (i < n4) {
    float4 v = ((const float4*)in)[i];
    float4 o;
    o.x = fxp(v.x); o.y = fxp(v.y); o.z = fxp(v.z); o.w = fxp(v.w);
    ((float4*)out)[i] = o;
  }
}

// h0 -> hbuf buffer 0, layout [grp=8][buf=2][row=8][1024] fp16
__global__ void qh0_kernel(const float* __restrict__ in,
                           _Float16* __restrict__ hbuf) {
  int i = blockIdx.x * 256 + threadIdx.x;  // over 64*1024/4
  int col4 = i & 255, b = i >> 8;
  float4 v = ((const float4*)in)[i];
  h4 o;
  o[0] = (_Float16)fxp(v.x); o[1] = (_Float16)fxp(v.y);
  o[2] = (_Float16)fxp(v.z); o[3] = (_Float16)fxp(v.w);
  *(h4*)(hbuf + (size_t)(b >> 3) * 16384 + (b & 7) * 1024 + col4 * 4) = o;
}

// ---------------------------------------------------------------------------
// Persistent recurrence WITH pipelined fused input projection. 256 blocks x
// 256 threads, a255 pin -> 1 block/CU. Block = (grp = blockIdx&7, rank =
// blockIdx>>3); group owns batch rows 8g..8g+7; rank owns h-cols
// rank*32..+31 x 4 gates (128 W_hh rows + 128 W_ih rows in regs).
// Per step: w0 polls (no outstanding VMEM) -> barrier B -> stage h (R13
// verbatim) -> barrier C -> recurrence MFMA + gates (axc precomputed) ->
// publish h -> barrier A -> flag -> out stores -> TAIL: ax[t+1] MFMAs +
// x[t+2] load/ds_write (idle-window work).
// ---------------------------------------------------------------------------
__global__ __launch_bounds__(256, 1) void lstm_kernel(
    const _Float16* __restrict__ Whh,  // [4096][1024] quantized
    const float* __restrict__ bhh,     // [4096] quantized
    const _Float16* __restrict__ Xq,   // [16384][512], row m = t*64+b
    const _Float16* __restrict__ Wih,  // [4096][512] quantized
    const float* __restrict__ bih,     // [4096] quantized
    const float* __restrict__ c0,      // [64][1024]
    _Float16* __restrict__ hbuf,       // [8][2][8][1024] fp16
    float* __restrict__ out,           // [64][256][1024] ++ h_n ++ c_n
    unsigned* __restrict__ flags)      // [8][32]
{
  // Residency pin: force total regs/wave > 256 -> 1 wave/SIMD -> 1 block/CU.
  asm volatile("v_accvgpr_write_b32 a255, 0" ::: "a255");

  const int tid = threadIdx.x;
  const int lane = tid & 63;
  const int w = tid >> 6;
  const int cl = lane & 15, q = lane >> 4;
  const int g01 = (lane >> 3) & 1;
  const int c7 = lane & 7;

  const int grp = blockIdx.x & 7;    // batch octet
  const int rank = blockIdx.x >> 3;  // 32-column slice owner

  const int jbase = (rank << 5) + (w << 3);         // block/wave col base
  const int row0 = (g01 << 10) + jbase + c7;        // gates i/f
  const int row1 = ((g01 + 2) << 10) + jbase + c7;  // gates g/o

  // persistent B fragments: Whh 2 tiles x 32 k-steps = 256 regs,
  // Wih 2 tiles x 16 k-steps = 128 regs (unified VGPR/AGPR file).
  h8 B0[32], B1[32];
#pragma unroll
  for (int kt = 0; kt < 32; kt++) {
    B0[kt] = *(const h8*)(Whh + (size_t)row0 * 1024 + (kt << 5) + (q << 3));
    B1[kt] = *(const h8*)(Whh + (size_t)row1 * 1024 + (kt << 5) + (q << 3));
  }
  h8 C0[16], C1[16];
#pragma unroll
  for (int kt = 0; kt < 16; kt++) {
    C0[kt] = *(const h8*)(Wih + (size_t)row0 * 512 + (kt << 5) + (q << 3));
    C1[kt] = *(const h8*)(Wih + (size_t)row1 * 512 + (kt << 5) + (q << 3));
  }
  const float bh0 = bhh[row0], bh1 = bhh[row1];
  const float bx0 = bih[row0], bx1 = bih[row1];
  const int jc = jbase + c7;        // h column 0..1023
  const int lrow = ((q & 1) << 2);  // local batch row base (valid q<2)
  const bool writer = ((lane & 8) == 0) && (q < 2);

  float c_st[4], h_last[4];
#pragma unroll
  for (int r = 0; r < 4; r++) {
    c_st[r] = c0[((grp << 3) + lrow + r) * 1024 + jc];
    h_last[r] = 0.0f;
  }

  // LDS: hs [8][1032] h-stage (R6-verified pad) + per-wave publication tiles
  // + xs DOUBLE-buffered [2][8][520] x-stage (same conflict class).
  __shared__ alignas(16) _Float16 hs[8 * 1032 + 4 * 64];
  __shared__ alignas(16) _Float16 xs[2 * 8 * 520];
  const int arow = cl & 7;
  const u64* hb64 = (const u64*)hbuf;  // [grp: 4096][buf: 2048] u64s
  const u64* xq64 = (const u64*)Xq;    // [16384][128] u64s
  const int srow = tid >> 5, sc = tid & 31;
  const size_t lsrc = (size_t)grp * 4096 + (size_t)(srow << 8) + sc;
  _Float16* ldst = hs + srow * 1032 + (sc << 2);
  _Float16* ts = hs + 8 * 1032 + w * 64;  // per-wave [8 rows][8 cols] tile

  unsigned* myflag = flags + (grp << 5) + rank;
  const u64* f2 = (const u64*)(flags + (grp << 5));  // 16 u64 per group

  // ---- prologue: stage xs[0] (x[0]) and xs[1] (x[1]), compute ax[0] ------
#pragma unroll
  for (int s = 0; s < 2; s++) {
    const u64* xsrc = xq64 + ((size_t)(s << 6) + (grp << 3) + srow) * 128 + sc;
    u64 x0 = xsrc[0], x1 = xsrc[32], x2 = xsrc[64], x3 = xsrc[96];
    _Float16* xd = xs + s * 4160 + srow * 520 + (sc << 2);
    *(u64*)(xd + 0 * 128) = x0;
    *(u64*)(xd + 1 * 128) = x1;
    *(u64*)(xd + 2 * 128) = x2;
    *(u64*)(xd + 3 * 128) = x3;
  }
  __syncthreads();
  f4 axc0 = {}, axc1 = {};
#pragma unroll
  for (int kt = 0; kt < 16; kt++) {
    h8 xv = *(const h8*)(xs + arow * 520 + (kt << 5) + (q << 3));
    axc0 = MFMA16(xv, C0[kt], axc0);
    axc1 = MFMA16(xv, C1[kt], axc1);
  }

  for (int t = 0; t < 256; t++) {
    if (t) {
      if (w == 0) {
        const unsigned tt = (unsigned)t;
        int it = 0;
        for (;;) {
          u64 v = __hip_atomic_load(&f2[lane & 15], __ATOMIC_RELAXED,
                                    __HIP_MEMORY_SCOPE_AGENT);
          bool ok = ((unsigned)v >= tt) && ((unsigned)(v >> 32) >= tt);
          if (__ballot(ok) == ~0ull) break;
          if (++it > (1 << 14)) break;  // hang insurance (loudly wrong)
          __builtin_amdgcn_s_sleep(1);
        }
      }
      __syncthreads();  // B
    }

    // ---- stage h_t (16KB): 8 coalesced 8B agent loads -> ds_write_b64 ----
    // (R13 verbatim: no x work in the critical stage phase)
    {
      const u64* src = hb64 + lsrc + (size_t)(t & 1) * 2048;
      u64 v0 = __hip_atomic_load(src + 0 * 32, __ATOMIC_RELAXED, __HIP_MEMORY_SCOPE_AGENT);
      u64 v1 = __hip_atomic_load(src + 1 * 32, __ATOMIC_RELAXED, __HIP_MEMORY_SCOPE_AGENT);
      u64 v2 = __hip_atomic_load(src + 2 * 32, __ATOMIC_RELAXED, __HIP_MEMORY_SCOPE_AGENT);
      u64 v3 = __hip_atomic_load(src + 3 * 32, __ATOMIC_RELAXED, __HIP_MEMORY_SCOPE_AGENT);
      u64 v4 = __hip_atomic_load(src + 4 * 32, __ATOMIC_RELAXED, __HIP_MEMORY_SCOPE_AGENT);
      u64 v5 = __hip_atomic_load(src + 5 * 32, __ATOMIC_RELAXED, __HIP_MEMORY_SCOPE_AGENT);
      u64 v6 = __hip_atomic_load(src + 6 * 32, __ATOMIC_RELAXED, __HIP_MEMORY_SCOPE_AGENT);
      u64 v7 = __hip_atomic_load(src + 7 * 32, __ATOMIC_RELAXED, __HIP_MEMORY_SCOPE_AGENT);
      *(u64*)(ldst + 0 * 128) = v0;
      *(u64*)(ldst + 1 * 128) = v1;
      *(u64*)(ldst + 2 * 128) = v2;
      *(u64*)(ldst + 3 * 128) = v3;
      *(u64*)(ldst + 4 * 128) = v4;
      *(u64*)(ldst + 5 * 128) = v5;
      *(u64*)(ldst + 6 * 128) = v6;
      *(u64*)(ldst + 7 * 128) = v7;
    }
    __syncthreads();  // C

    // ---- MFMA: recurrence only (gx already in axc registers) -------------
    f4 a0 = {}, a1 = {}, a2 = {}, a3 = {};
#pragma unroll
    for (int kt = 0; kt < 32; kt++) {
      h8 av = *(const h8*)(hs + arow * 1032 + (kt << 5) + (q << 3));
      if (kt & 1) { a1 = MFMA16(av, B0[kt], a1); a3 = MFMA16(av, B1[kt], a3); }
      else        { a0 = MFMA16(av, B0[kt], a0); a2 = MFMA16(av, B1[kt], a2); }
    }
    f4 g0 = a0 + a1;
    f4 g1 = a2 + a3;

    _Float16* hbw = hbuf + (size_t)grp * 16384 + ((t + 1) & 1) * 8192;
#pragma unroll
    for (int r = 0; r < 4; r++) {
      float xg0 = fxp(axc0[r] + bx0);                // gx, gate i/f
      float xg1 = fxp(axc1[r] + bx1);                // gx, gate g/o
      float gv0 = fxp(xg0 + fxp(g0[r] + bh0));       // i or f
      float gv1 = fxp(xg1 + fxp(g1[r] + bh1));       // g or o
      float s0 = fxp_rnd(hsig(gv0));                        // in [0,1]
      float s1t = fxp_rnd(fminf(fmaxf(gv1, -1.0f), 1.0f));  // in [-1,1]
      float s1s = fxp_rnd(hsig(gv1));
      float s1 = (lane & 8) ? s1s : s1t;
      float p0 = __shfl_xor(s0, 8);
      float p1 = __shfl_xor(s1, 8);
      float iv = writer ? s0 : p0;
      float fv = writer ? p0 : s0;
      float gv = writer ? s1 : p1;
      float ov = writer ? p1 : s1;
      float cn = fxp(fv * c_st[r] + iv * gv);
      c_st[r] = cn;
      float hn = fxp_rnd(ov * fminf(fmaxf(cn, -1.0f), 1.0f));  // in [-1,1]
      h_last[r] = hn;
      // R13: deposit h into the per-wave LDS tile (2 lanes/bank, free)
      if (writer) ts[(lrow + r) * 8 + c7] = (_Float16)hn;
    }
    // wave-local: wait for the tile, lanes 0-15 transpose-read (b64) and
    // issue 16 contiguous 8B agent stores (two lanes = 16B run per row).
    asm volatile("s_waitcnt lgkmcnt(0)" ::: "memory");
    if (lane < 16) {
      u64 hv = *(const u64*)(ts + (lane >> 1) * 8 + ((lane & 1) << 2));
      __hip_atomic_store(
          (u64*)&hbw[(lane >> 1) * 1024 + jbase + ((lane & 1) << 2)], hv,
          __ATOMIC_RELAXED, __HIP_MEMORY_SCOPE_AGENT);
    }
    __syncthreads();  // A: drains the h stores (out stores not yet issued)
    if (tid == 0)
      __hip_atomic_store(myflag, (unsigned)(t + 1), __ATOMIC_RELAXED,
                         __HIP_MEMORY_SCOPE_AGENT);
    // out stores after the flag: drain in the tail (idle window)
    if (writer) {
#pragma unroll
      for (int r = 0; r < 4; r++)
        __builtin_nontemporal_store(
            h_last[r],
            &out[((size_t)((grp << 3) + lrow + r) * 256 + t) * 1024 + jc]);
    }

    // ---- TAIL (idle window): ax[t+1] + x[t+2] stage -----------------------
    // Reads xs[(t+1)&1] (staged in tail t-1 or prologue; barrier-separated
    // from its writers). Writes xs[t&1] for t+2 (its tail-(t-1) readers
    // completed before barrier B(t)). The ds_write's vmcnt dependency drains
    // the x loads AND the out stores -> w0 polls with 0 outstanding VMEM.
    if (t < 255) {
      u64 x0, x1, x2, x3;
      const bool more = (t < 254);
      if (more) {
        const u64* xsrc =
            xq64 + ((size_t)((t + 2) << 6) + (grp << 3) + srow) * 128 + sc;
        x0 = xsrc[0]; x1 = xsrc[32]; x2 = xsrc[64]; x3 = xsrc[96];
      }
      const _Float16* xb = xs + ((t + 1) & 1) * 4160;
      f4 n0 = {}, n1 = {};
#pragma unroll
      for (int kt = 0; kt < 16; kt++) {
        h8 xv = *(const h8*)(xb + arow * 520 + (kt << 5) + (q << 3));
        n0 = MFMA16(xv, C0[kt], n0);
        n1 = MFMA16(xv, C1[kt], n1);
      }
      axc0 = n0;
      axc1 = n1;
      if (more) {
        _Float16* xd = xs + (t & 1) * 4160 + srow * 520 + (sc << 2);
        *(u64*)(xd + 0 * 128) = x0;
        *(u64*)(xd + 1 * 128) = x1;
        *(u64*)(xd + 2 * 128) = x2;
        *(u64*)(xd + 3 * 128) = x3;
      }
    }
  }

  if (writer) {
#pragma unroll
    for (int r = 0; r < 4; r++) {
      out[16777216 + (size_t)((grp << 3) + lrow + r) * 1024 + jc] = h_last[r];
      out[16777216 + 65536 + (size_t)((grp << 3) + lrow + r) * 1024 + jc] =
          c_st[r];
    }
  }
}

// ---------------------------------------------------------------------------
extern "C" void kernel_launch(void* const* d_in, const int* in_sizes, int n_in,
                              void* d_out, int out_size, void* d_ws,
                              size_t ws_size, hipStream_t stream) {
  const float* x    = (const float*)d_in[0];
  const float* w_ih = (const float*)d_in[1];
  const float* w_hh = (const float*)d_in[2];
  const float* b_ih = (const float*)d_in[3];
  const float* b_hh = (const float*)d_in[4];
  const float* h0   = (const float*)d_in[5];
  const float* c0   = (const float*)d_in[6];
  float* out = (float*)d_out;

  // workspace layout (bytes)
  char* ws = (char*)d_ws;
  unsigned* flags = (unsigned*)ws;                    // [8][32] u32 = 1 KB
  _Float16* hbuf  = (_Float16*)(ws + 2048);           // 8*2*8*1024*2 = 256 KB
  _Float16* whhq  = (_Float16*)(ws + 264192);         // 8 MB
  _Float16* wihq  = (_Float16*)(ws + 8652800);        // 4 MB
  float*    bihq  = (float*)(ws + 12847104);          // 16 KB
  float*    bhhq  = (float*)(ws + 12863488);          // 16 KB
  _Float16* xq    = (_Float16*)(ws + 12879872);       // 16 MB

  hipMemsetAsync(flags, 0, 2048, stream);
  qf16_kernel<<<dim3(4096), 256, 0, stream>>>(w_hh, whhq, 4194304 / 4);
  qf16_kernel<<<dim3(2048), 256, 0, stream>>>(w_ih, wihq, 2097152 / 4);
  qx_kernel<<<dim3(8192), 256, 0, stream>>>(x, xq);
  qh0_kernel<<<dim3(64), 256, 0, stream>>>(h0, hbuf);
  qf32_kernel<<<dim3(4), 256, 0, stream>>>(b_ih, bihq, 4096 / 4);
  qf32_kernel<<<dim3(4), 256, 0, stream>>>(b_hh, bhhq, 4096 / 4);
  lstm_kernel<<<dim3(256), 256, 0, stream>>>(whhq, bhhq, xq, wihq, bihq, c0,
                                             hbuf, out, flags);
}